// Round 4
// baseline (155.915 us; speedup 1.0000x reference)
//
#include <hip/hip_runtime.h>
#include <hip/hip_bf16.h>
#include <math.h>

// Problem constants (B=512, D=768, H=256)
#define B 512
#define D 768
#define H 256
#define NN 128          // n = B/4
#define MM 256          // m = B/2
#define P_PAIRS 57280   // sum_{i=0}^{127} (511 - i) = 895 * 64 exactly
#define NPBLK 895       // pair-tiles of 64

typedef __attribute__((ext_vector_type(8))) __bf16 bf16x8;
typedef __attribute__((ext_vector_type(4))) __bf16 bf16x4;
typedef __attribute__((ext_vector_type(4))) float f32x4;

// MFMA 16x16x32 bf16 layouts (verified):
//   A[m = lane&15][k = (lane>>4)*8 + j]  (8 bf16/lane, contiguous k)
//   B[k][n] loaded from row-major [n][k] with the same per-lane pattern
//   C/D: col = lane&15, row = (lane>>4)*4 + reg

// ---------------- K1: normalize z -> bf16, W1/W2 -> bf16, zero stats ----------------
__global__ __launch_bounds__(256) void k_prep(const float* __restrict__ emb,
                                              const float* __restrict__ W1,
                                              const float* __restrict__ W2,
                                              __bf16* __restrict__ zbf,
                                              __bf16* __restrict__ W1b,
                                              __bf16* __restrict__ W2b,
                                              float* __restrict__ stats) {
    int bx = blockIdx.x;
    int t = threadIdx.x;
    if (bx < B) {
        float4 v4 = make_float4(0.f, 0.f, 0.f, 0.f);
        float ss = 0.f;
        if (t < D / 4) {
            v4 = *(const float4*)(emb + bx * D + 4 * t);
            ss = v4.x * v4.x + v4.y * v4.y + v4.z * v4.z + v4.w * v4.w;
        }
        __shared__ float red[256];
        red[t] = ss;
        __syncthreads();
        for (int s = 128; s > 0; s >>= 1) {
            if (t < s) red[t] += red[t + s];
            __syncthreads();
        }
        float inv = 1.0f / fmaxf(sqrtf(red[0]), 1e-12f);
        if (t < D / 4) {
            bf16x4 o;
            o[0] = (__bf16)(v4.x * inv); o[1] = (__bf16)(v4.y * inv);
            o[2] = (__bf16)(v4.z * inv); o[3] = (__bf16)(v4.w * inv);
            *(bf16x4*)(zbf + bx * D + 4 * t) = o;
        }
    } else if (bx < B + 64) {
        int e4 = (bx - B) * 256 + t;     // W2: 16384 float4 groups
        float4 w = *(const float4*)(W2 + 4 * e4);
        bf16x4 o;
        o[0] = (__bf16)w.x; o[1] = (__bf16)w.y; o[2] = (__bf16)w.z; o[3] = (__bf16)w.w;
        *(bf16x4*)(W2b + 4 * e4) = o;
    } else if (bx < B + 64 + 2 * H) {
        // W1 convert+restack: W1b[n][k] = W1[n&255][(n>>8)*768 + k]
        int n = bx - B - 64;
        if (t < D / 4) {
            float4 w = *(const float4*)(W1 + (n & 255) * (2 * D) + (n >> 8) * D + 4 * t);
            bf16x4 o;
            o[0] = (__bf16)w.x; o[1] = (__bf16)w.y; o[2] = (__bf16)w.z; o[3] = (__bf16)w.w;
            *(bf16x4*)(W1b + n * D + 4 * t) = o;
        }
    } else {
        stats[t] = 0.f;                   // expsum[128] | slog[128]
        if (t == 0) { stats[256] = 0.f; ((int*)stats)[257] = 0; }
    }
}

// ---------------- K2: fused similarity stats + U'/V GEMMs ----------------
__global__ __launch_bounds__(128) void k_sim_uv(const __bf16* __restrict__ zbf,
                                                const __bf16* __restrict__ W1b,
                                                const float* __restrict__ b1,
                                                __bf16* __restrict__ Up,
                                                __bf16* __restrict__ Vv,
                                                float* __restrict__ expsum,
                                                float* __restrict__ slog) {
    int bx = blockIdx.x;
    int w = threadIdx.x >> 6;
    int lane = threadIdx.x & 63;
    int r = lane & 15, q = lane >> 4;

    if (bx < 32) {
        // ---- similarity stats: m-tile 16 (rows<128), wave n-tile 64 ----
        int m0 = (bx >> 2) * 16;
        int n0 = (bx & 3) * 128 + w * 64;
        f32x4 acc[4] = {};
        const __bf16* Ab = zbf + (m0 + r) * D + 8 * q;
        #pragma unroll 4
        for (int s = 0; s < D / 32; s++) {
            bf16x8 a = *(const bf16x8*)(Ab + 32 * s);
            #pragma unroll
            for (int nt = 0; nt < 4; nt++) {
                bf16x8 b = *(const bf16x8*)(zbf + (n0 + 16 * nt + r) * D + 8 * q + 32 * s);
                acc[nt] = __builtin_amdgcn_mfma_f32_16x16x32_bf16(a, b, acc[nt], 0, 0, 0);
            }
        }
        #pragma unroll
        for (int rr = 0; rr < 4; rr++) {
            int irow = m0 + q * 4 + rr;
            float es = 0.f, sl = 0.f;
            #pragma unroll
            for (int nt = 0; nt < 4; nt++) {
                int kcol = n0 + nt * 16 + r;
                float C = acc[nt][rr];
                if (kcol != irow) es += expf(2.f * C);
                if (kcol > irow && kcol < NN) sl += 2.f * C;
            }
            #pragma unroll
            for (int m = 1; m <= 8; m <<= 1) {
                es += __shfl_xor(es, m);
                sl += __shfl_xor(sl, m);
            }
            if (r == 0) {
                atomicAdd(&expsum[irow], es);
                atomicAdd(&slog[irow], sl);
            }
        }
    } else {
        // ---- U' = z@W1a^T + b1 ; V = z@W1b^T  (bf16 out) ----
        int bxu = bx - 32;
        int m0 = (bxu >> 3) * 32 + 16 * w;
        int n0 = (bxu & 7) * 64;
        f32x4 acc[4] = {};
        const __bf16* Ab = zbf + (m0 + r) * D + 8 * q;
        #pragma unroll 4
        for (int s = 0; s < D / 32; s++) {
            bf16x8 a = *(const bf16x8*)(Ab + 32 * s);
            #pragma unroll
            for (int nt = 0; nt < 4; nt++) {
                bf16x8 b = *(const bf16x8*)(W1b + (n0 + 16 * nt + r) * D + 8 * q + 32 * s);
                acc[nt] = __builtin_amdgcn_mfma_f32_16x16x32_bf16(a, b, acc[nt], 0, 0, 0);
            }
        }
        #pragma unroll
        for (int nt = 0; nt < 4; nt++) {
            int n = n0 + 16 * nt + r;
            float bias = (n < H) ? b1[n] : 0.f;
            #pragma unroll
            for (int rr = 0; rr < 4; rr++) {
                int m = m0 + 4 * q + rr;
                float C = acc[nt][rr] + bias;
                if (n < H) Up[m * H + n] = (__bf16)C;
                else       Vv[m * H + (n - H)] = (__bf16)C;
            }
        }
    }
}

// ---------------- K3: pair MLP, pair-flat 64-row tiles, W2 streamed from L2 ----------------
// 895 blocks x 256 thr (4 waves; wave w -> output cols 64w..64w+63)
__global__ __launch_bounds__(256, 2) void k_pairs(const __bf16* __restrict__ Up,
                                                  const __bf16* __restrict__ Vv,
                                                  const __bf16* __restrict__ W2b,
                                                  const float* __restrict__ b2,
                                                  const float* __restrict__ W3,
                                                  const float* __restrict__ b3,
                                                  float* __restrict__ expsum,
                                                  float* __restrict__ slog,
                                                  float* __restrict__ bce,
                                                  int* __restrict__ counter,
                                                  float* __restrict__ out) {
    __shared__ __bf16 h1[64][264];       // 33.8 KB; row stride 528 B
    __shared__ int jj_s[64];
    __shared__ float redbuf[4][64];
    __shared__ float red[128];
    __shared__ int islast;

    int tid = threadIdx.x;
    int w = tid >> 6, lane = tid & 63;
    int r = lane & 15, q = lane >> 4;
    int p0 = blockIdx.x * 64;

    // ---- (i,j) for row tid: f(i) = i*(1023-i)/2 pairs precede row-block i ----
    if (tid < 64) {
        int p = p0 + tid;
        float disc = 1046529.f - 8.f * (float)p;   // exact in fp32
        int i = (int)((1023.f - sqrtf(disc)) * 0.5f);
        if (i < 0) i = 0;
        if (i > NN - 1) i = NN - 1;
        while (i > 0 && i * (1023 - i) / 2 > p) i--;
        while ((i + 1) * (1022 - i) / 2 <= p) i++;
        int j = i + 1 + (p - i * (1023 - i) / 2);
        jj_s[tid] = (i << 16) | j;
    }
    __syncthreads();

    // ---- stage h1[t][:] = relu(U'[i_t] + V[j_t]) in bf16 ----
    {
        int t = tid & 63, g = tid >> 6;
        int ij = jj_s[t];
        int i = ij >> 16, j = ij & 0xffff;
        const __bf16* up = Up + i * H + 64 * g;
        const __bf16* vp = Vv + j * H + 64 * g;
        #pragma unroll
        for (int c8 = 0; c8 < 8; c8++) {
            bf16x8 u8 = *(const bf16x8*)(up + 8 * c8);
            bf16x8 v8 = *(const bf16x8*)(vp + 8 * c8);
            bf16x8 hv;
            #pragma unroll
            for (int e = 0; e < 8; e++)
                hv[e] = (__bf16)fmaxf((float)u8[e] + (float)v8[e], 0.f);
            *(bf16x8*)&h1[t][64 * g + 8 * c8] = hv;
        }
    }
    __syncthreads();

    // ---- MFMA: C[64 pairs][64 cols per wave] = h1 @ W2^T ----
    f32x4 acc[4][4] = {};                // [mt][nt]
    const __bf16* wb = W2b + (64 * w + r) * H + 8 * q;
    #pragma unroll
    for (int s = 0; s < 8; s++) {
        bf16x8 a[4], b[4];
        #pragma unroll
        for (int mt = 0; mt < 4; mt++)
            a[mt] = *(const bf16x8*)&h1[16 * mt + r][32 * s + 8 * q];
        #pragma unroll
        for (int nt = 0; nt < 4; nt++)
            b[nt] = *(const bf16x8*)(wb + 16 * nt * H + 32 * s);
        #pragma unroll
        for (int mt = 0; mt < 4; mt++)
            #pragma unroll
            for (int nt = 0; nt < 4; nt++)
                acc[mt][nt] = __builtin_amdgcn_mfma_f32_16x16x32_bf16(a[mt], b[nt], acc[mt][nt], 0, 0, 0);
    }

    // ---- epilogue: h2 = relu(C + b2), partial logit = sum_n h2*W3 ----
    float part[4][4] = {};               // [mt][rr]
    #pragma unroll
    for (int nt = 0; nt < 4; nt++) {
        int n = 64 * w + 16 * nt + r;
        float b2v = b2[n], w3v = W3[n];
        #pragma unroll
        for (int mt = 0; mt < 4; mt++)
            #pragma unroll
            for (int rr = 0; rr < 4; rr++) {
                float h2 = fmaxf(acc[mt][nt][rr] + b2v, 0.f);
                part[mt][rr] += h2 * w3v;
            }
    }
    #pragma unroll
    for (int mt = 0; mt < 4; mt++)
        #pragma unroll
        for (int rr = 0; rr < 4; rr++) {
            float v = part[mt][rr];
            #pragma unroll
            for (int m = 1; m <= 8; m <<= 1) v += __shfl_xor(v, m);
            if (r == 0) redbuf[w][16 * mt + 4 * q + rr] = v;
        }
    __syncthreads();

    if (tid < 64) {
        int j = jj_s[tid] & 0xffff;
        float logit = redbuf[0][tid] + redbuf[1][tid] +
                      redbuf[2][tid] + redbuf[3][tid] + b3[0];
        float label = (j < MM) ? 1.f : 0.f;
        float lsum = fmaxf(logit, 0.f) - logit * label +
                     log1pf(expf(-fabsf(logit)));
        #pragma unroll
        for (int off = 32; off > 0; off >>= 1) lsum += __shfl_down(lsum, off);
        if (tid == 0) atomicAdd(bce, lsum);
    }

    // ---- last-block final combine ----
    __threadfence();
    if (tid == 0) {
        int old = atomicAdd(counter, 1);
        islast = (old == NPBLK - 1);
    }
    __syncthreads();
    if (islast) {
        if (tid < 128)
            red[tid] = (float)(NN - 1 - tid) * logf(expsum[tid]) - slog[tid];
        __syncthreads();
        for (int s = 64; s > 0; s >>= 1) {
            if (tid < s && tid + s < 128) red[tid] += red[tid + s];
            __syncthreads();
        }
        if (tid == 0) {
            float closs = (-2.0f * (float)(NN - 1) / (float)NN) * red[0];
            float bv = atomicAdd(bce, 0.f);
            out[0] = closs + bv / (float)P_PAIRS;
        }
    }
}

extern "C" void kernel_launch(void* const* d_in, const int* in_sizes, int n_in,
                              void* d_out, int out_size, void* d_ws, size_t ws_size,
                              hipStream_t stream) {
    const float* emb = (const float*)d_in[0];
    const float* W1  = (const float*)d_in[1];
    const float* b1  = (const float*)d_in[2];
    const float* W2  = (const float*)d_in[3];
    const float* b2  = (const float*)d_in[4];
    const float* W3  = (const float*)d_in[5];
    const float* b3  = (const float*)d_in[6];
    float* out = (float*)d_out;

    float* ws = (float*)d_ws;
    float* stats  = ws;
    float* expsum = ws;
    float* slog   = ws + 128;
    float* bce    = ws + 256;
    int*   counter= (int*)(ws + 257);
    __bf16* zbf = (__bf16*)(ws + 512);           // 512*768
    __bf16* W1b = zbf + B * D;                   // 512*768
    __bf16* W2b = W1b + 2 * H * D;               // 256*256
    __bf16* Up  = W2b + H * H;                   // 512*256
    __bf16* Vv  = Up + B * H;                    // 512*256

    k_prep<<<B + 64 + 2 * H + 1, 256, 0, stream>>>(emb, W1, W2, zbf, W1b, W2b, stats);
    k_sim_uv<<<160, 128, 0, stream>>>(zbf, W1b, b1, Up, Vv, expsum, slog);
    k_pairs<<<NPBLK, 256, 0, stream>>>(Up, Vv, W2b, b2, W3, b3,
                                       expsum, slog, bce, counter, out);
}

// Round 5
// 108.648 us; speedup vs baseline: 1.4350x; 1.4350x over previous
//
#include <hip/hip_runtime.h>
#include <hip/hip_bf16.h>
#include <math.h>

// Problem constants (B=512, D=768, H=256)
#define B 512
#define D 768
#define H 256
#define NN 128          // n = B/4
#define MM 256          // m = B/2
#define P_PAIRS 57280   // sum_{i=0}^{127} (511 - i) = 895 * 64 exactly
#define NPBLK 895       // pair-tiles of 64

typedef __attribute__((ext_vector_type(8))) __bf16 bf16x8;
typedef __attribute__((ext_vector_type(4))) __bf16 bf16x4;
typedef __attribute__((ext_vector_type(4))) float f32x4;

// MFMA 16x16x32 bf16 layouts (verified):
//   A[m = lane&15][k = (lane>>4)*8 + j]  (8 bf16/lane, contiguous k)
//   B[k][n] loaded from row-major [n][k] with the same per-lane pattern
//   C/D: col = lane&15, row = (lane>>4)*4 + reg

// ---------------- K1: normalize z -> bf16, W1/W2 -> bf16 ----------------
__global__ __launch_bounds__(256) void k_prep(const float* __restrict__ emb,
                                              const float* __restrict__ W1,
                                              const float* __restrict__ W2,
                                              __bf16* __restrict__ zbf,
                                              __bf16* __restrict__ W1b,
                                              __bf16* __restrict__ W2b) {
    int bx = blockIdx.x;
    int t = threadIdx.x;
    if (bx < B) {
        float4 v4 = make_float4(0.f, 0.f, 0.f, 0.f);
        float ss = 0.f;
        if (t < D / 4) {
            v4 = *(const float4*)(emb + bx * D + 4 * t);
            ss = v4.x * v4.x + v4.y * v4.y + v4.z * v4.z + v4.w * v4.w;
        }
        __shared__ float red[256];
        red[t] = ss;
        __syncthreads();
        for (int s = 128; s > 0; s >>= 1) {
            if (t < s) red[t] += red[t + s];
            __syncthreads();
        }
        float inv = 1.0f / fmaxf(sqrtf(red[0]), 1e-12f);
        if (t < D / 4) {
            bf16x4 o;
            o[0] = (__bf16)(v4.x * inv); o[1] = (__bf16)(v4.y * inv);
            o[2] = (__bf16)(v4.z * inv); o[3] = (__bf16)(v4.w * inv);
            *(bf16x4*)(zbf + bx * D + 4 * t) = o;
        }
    } else if (bx < B + 64) {
        int e4 = (bx - B) * 256 + t;     // W2: 16384 float4 groups
        float4 w = *(const float4*)(W2 + 4 * e4);
        bf16x4 o;
        o[0] = (__bf16)w.x; o[1] = (__bf16)w.y; o[2] = (__bf16)w.z; o[3] = (__bf16)w.w;
        *(bf16x4*)(W2b + 4 * e4) = o;
    } else {
        // W1 convert+restack: W1b[n][k] = W1[n&255][(n>>8)*768 + k]
        int n = bx - B - 64;
        if (t < D / 4) {
            float4 w = *(const float4*)(W1 + (n & 255) * (2 * D) + (n >> 8) * D + 4 * t);
            bf16x4 o;
            o[0] = (__bf16)w.x; o[1] = (__bf16)w.y; o[2] = (__bf16)w.z; o[3] = (__bf16)w.w;
            *(bf16x4*)(W1b + n * D + 4 * t) = o;
        }
    }
}

// ---------------- K2: fused similarity stats + U'/V GEMMs (partials, no atomics) ----------------
__global__ __launch_bounds__(128) void k_sim_uv(const __bf16* __restrict__ zbf,
                                                const __bf16* __restrict__ W1b,
                                                const float* __restrict__ b1,
                                                __bf16* __restrict__ Up,
                                                __bf16* __restrict__ Vv,
                                                float* __restrict__ esp,   // [8][128]
                                                float* __restrict__ slp) { // [8][128]
    int bx = blockIdx.x;
    int w = threadIdx.x >> 6;
    int lane = threadIdx.x & 63;
    int r = lane & 15, q = lane >> 4;

    if (bx < 32) {
        // ---- similarity stats: m-tile 16 (rows<128), wave n-tile 64 ----
        int m0 = (bx >> 2) * 16;
        int n0 = (bx & 3) * 128 + w * 64;
        int slot = (bx & 3) * 2 + w;     // 8 partial slots per row
        f32x4 acc[4] = {};
        const __bf16* Ab = zbf + (m0 + r) * D + 8 * q;
        #pragma unroll 4
        for (int s = 0; s < D / 32; s++) {
            bf16x8 a = *(const bf16x8*)(Ab + 32 * s);
            #pragma unroll
            for (int nt = 0; nt < 4; nt++) {
                bf16x8 b = *(const bf16x8*)(zbf + (n0 + 16 * nt + r) * D + 8 * q + 32 * s);
                acc[nt] = __builtin_amdgcn_mfma_f32_16x16x32_bf16(a, b, acc[nt], 0, 0, 0);
            }
        }
        #pragma unroll
        for (int rr = 0; rr < 4; rr++) {
            int irow = m0 + q * 4 + rr;
            float es = 0.f, sl = 0.f;
            #pragma unroll
            for (int nt = 0; nt < 4; nt++) {
                int kcol = n0 + nt * 16 + r;
                float C = acc[nt][rr];
                if (kcol != irow) es += expf(2.f * C);
                if (kcol > irow && kcol < NN) sl += 2.f * C;
            }
            #pragma unroll
            for (int m = 1; m <= 8; m <<= 1) {
                es += __shfl_xor(es, m);
                sl += __shfl_xor(sl, m);
            }
            if (r == 0) {
                esp[slot * NN + irow] = es;
                slp[slot * NN + irow] = sl;
            }
        }
    } else {
        // ---- U' = z@W1a^T + b1 ; V = z@W1b^T  (bf16 out) ----
        int bxu = bx - 32;
        int m0 = (bxu >> 3) * 32 + 16 * w;
        int n0 = (bxu & 7) * 64;
        f32x4 acc[4] = {};
        const __bf16* Ab = zbf + (m0 + r) * D + 8 * q;
        #pragma unroll 4
        for (int s = 0; s < D / 32; s++) {
            bf16x8 a = *(const bf16x8*)(Ab + 32 * s);
            #pragma unroll
            for (int nt = 0; nt < 4; nt++) {
                bf16x8 b = *(const bf16x8*)(W1b + (n0 + 16 * nt + r) * D + 8 * q + 32 * s);
                acc[nt] = __builtin_amdgcn_mfma_f32_16x16x32_bf16(a, b, acc[nt], 0, 0, 0);
            }
        }
        #pragma unroll
        for (int nt = 0; nt < 4; nt++) {
            int n = n0 + 16 * nt + r;
            float bias = (n < H) ? b1[n] : 0.f;
            #pragma unroll
            for (int rr = 0; rr < 4; rr++) {
                int m = m0 + 4 * q + rr;
                float C = acc[nt][rr] + bias;
                if (n < H) Up[m * H + n] = (__bf16)C;
                else       Vv[m * H + (n - H)] = (__bf16)C;
            }
        }
    }
}

// ---------------- K3: pair MLP, pair-flat 64-row tiles; partial BCE store only ----------------
// 895 blocks x 256 thr (4 waves; wave w -> output cols 64w..64w+63)
__global__ __launch_bounds__(256, 2) void k_pairs(const __bf16* __restrict__ Up,
                                                  const __bf16* __restrict__ Vv,
                                                  const __bf16* __restrict__ W2b,
                                                  const float* __restrict__ b2,
                                                  const float* __restrict__ W3,
                                                  const float* __restrict__ b3,
                                                  float* __restrict__ bcepart) {
    __shared__ __bf16 h1[64][264];       // 33.8 KB; row stride 528 B
    __shared__ int jj_s[64];
    __shared__ float redbuf[4][64];

    int tid = threadIdx.x;
    int w = tid >> 6, lane = tid & 63;
    int r = lane & 15, q = lane >> 4;
    int p0 = blockIdx.x * 64;

    // ---- (i,j) for row tid: i*(1023-i)/2 pairs precede row-block i ----
    if (tid < 64) {
        int p = p0 + tid;
        float disc = 1046529.f - 8.f * (float)p;   // 1023^2 - 8p, exact in fp32
        int i = (int)((1023.f - sqrtf(disc)) * 0.5f);
        if (i < 0) i = 0;
        if (i > NN - 1) i = NN - 1;
        while (i > 0 && i * (1023 - i) / 2 > p) i--;
        while ((i + 1) * (1022 - i) / 2 <= p) i++;
        int j = i + 1 + (p - i * (1023 - i) / 2);
        jj_s[tid] = (i << 16) | j;
    }
    __syncthreads();

    // ---- stage h1[t][:] = relu(U'[i_t] + V[j_t]) in bf16 ----
    {
        int t = tid & 63, g = tid >> 6;
        int ij = jj_s[t];
        int i = ij >> 16, j = ij & 0xffff;
        const __bf16* up = Up + i * H + 64 * g;
        const __bf16* vp = Vv + j * H + 64 * g;
        #pragma unroll
        for (int c8 = 0; c8 < 8; c8++) {
            bf16x8 u8 = *(const bf16x8*)(up + 8 * c8);
            bf16x8 v8 = *(const bf16x8*)(vp + 8 * c8);
            bf16x8 hv;
            #pragma unroll
            for (int e = 0; e < 8; e++)
                hv[e] = (__bf16)fmaxf((float)u8[e] + (float)v8[e], 0.f);
            *(bf16x8*)&h1[t][64 * g + 8 * c8] = hv;
        }
    }
    __syncthreads();

    // ---- MFMA: C[64 pairs][64 cols per wave] = h1 @ W2^T ----
    f32x4 acc[4][4] = {};                // [mt][nt]
    const __bf16* wb = W2b + (64 * w + r) * H + 8 * q;
    #pragma unroll
    for (int s = 0; s < 8; s++) {
        bf16x8 a[4], b[4];
        #pragma unroll
        for (int mt = 0; mt < 4; mt++)
            a[mt] = *(const bf16x8*)&h1[16 * mt + r][32 * s + 8 * q];
        #pragma unroll
        for (int nt = 0; nt < 4; nt++)
            b[nt] = *(const bf16x8*)(wb + 16 * nt * H + 32 * s);
        #pragma unroll
        for (int mt = 0; mt < 4; mt++)
            #pragma unroll
            for (int nt = 0; nt < 4; nt++)
                acc[mt][nt] = __builtin_amdgcn_mfma_f32_16x16x32_bf16(a[mt], b[nt], acc[mt][nt], 0, 0, 0);
    }

    // ---- epilogue: h2 = relu(C + b2), partial logit = sum_n h2*W3 ----
    float part[4][4] = {};               // [mt][rr]
    #pragma unroll
    for (int nt = 0; nt < 4; nt++) {
        int n = 64 * w + 16 * nt + r;
        float b2v = b2[n], w3v = W3[n];
        #pragma unroll
        for (int mt = 0; mt < 4; mt++)
            #pragma unroll
            for (int rr = 0; rr < 4; rr++) {
                float h2 = fmaxf(acc[mt][nt][rr] + b2v, 0.f);
                part[mt][rr] += h2 * w3v;
            }
    }
    #pragma unroll
    for (int mt = 0; mt < 4; mt++)
        #pragma unroll
        for (int rr = 0; rr < 4; rr++) {
            float v = part[mt][rr];
            #pragma unroll
            for (int m = 1; m <= 8; m <<= 1) v += __shfl_xor(v, m);
            if (r == 0) redbuf[w][16 * mt + 4 * q + rr] = v;
        }
    __syncthreads();

    if (tid < 64) {
        int j = jj_s[tid] & 0xffff;
        float logit = redbuf[0][tid] + redbuf[1][tid] +
                      redbuf[2][tid] + redbuf[3][tid] + b3[0];
        float label = (j < MM) ? 1.f : 0.f;
        float lsum = fmaxf(logit, 0.f) - logit * label +
                     log1pf(expf(-fabsf(logit)));
        #pragma unroll
        for (int off = 32; off > 0; off >>= 1) lsum += __shfl_down(lsum, off);
        if (tid == 0) bcepart[blockIdx.x] = lsum;   // plain store, no atomic
    }
}

// ---------------- K4: final combine ----------------
__global__ __launch_bounds__(256) void k_final(const float* __restrict__ esp,
                                               const float* __restrict__ slp,
                                               const float* __restrict__ bcepart,
                                               float* __restrict__ out) {
    __shared__ float red[256];
    int t = threadIdx.x;

    // sum BCE partials
    float s = 0.f;
    for (int p = t; p < NPBLK; p += 256) s += bcepart[p];
    red[t] = s;
    __syncthreads();
    for (int st = 128; st > 0; st >>= 1) {
        if (t < st) red[t] += red[t + st];
        __syncthreads();
    }
    float bce_total = red[0];
    __syncthreads();

    // fold contrastive partials
    float v = 0.f;
    if (t < NN) {
        float es = 0.f, sl = 0.f;
        #pragma unroll
        for (int s8 = 0; s8 < 8; s8++) {
            es += esp[s8 * NN + t];
            sl += slp[s8 * NN + t];
        }
        v = (float)(NN - 1 - t) * logf(es) - sl;
    }
    red[t] = v;
    __syncthreads();
    for (int st = 128; st > 0; st >>= 1) {
        if (t < st) red[t] += red[t + st];
        __syncthreads();
    }
    if (t == 0) {
        float closs = (-2.0f * (float)(NN - 1) / (float)NN) * red[0];
        out[0] = closs + bce_total / (float)P_PAIRS;
    }
}

extern "C" void kernel_launch(void* const* d_in, const int* in_sizes, int n_in,
                              void* d_out, int out_size, void* d_ws, size_t ws_size,
                              hipStream_t stream) {
    const float* emb = (const float*)d_in[0];
    const float* W1  = (const float*)d_in[1];
    const float* b1  = (const float*)d_in[2];
    const float* W2  = (const float*)d_in[3];
    const float* b2  = (const float*)d_in[4];
    const float* W3  = (const float*)d_in[5];
    const float* b3  = (const float*)d_in[6];
    float* out = (float*)d_out;

    float* ws = (float*)d_ws;
    float* esp     = ws;                         // 8*128
    float* slp     = ws + 1024;                  // 8*128
    float* bcepart = ws + 2048;                  // 895
    __bf16* zbf = (__bf16*)(ws + 3072);          // 512*768
    __bf16* W1b = zbf + B * D;                   // 512*768
    __bf16* W2b = W1b + 2 * H * D;               // 256*256
    __bf16* Up  = W2b + H * H;                   // 512*256
    __bf16* Vv  = Up + B * H;                    // 512*256

    k_prep<<<B + 64 + 2 * H, 256, 0, stream>>>(emb, W1, W2, zbf, W1b, W2b);
    k_sim_uv<<<160, 128, 0, stream>>>(zbf, W1b, b1, Up, Vv, esp, slp);
    k_pairs<<<NPBLK, 256, 0, stream>>>(Up, Vv, W2b, b2, W3, b3, bcepart);
    k_final<<<1, 256, 0, stream>>>(esp, slp, bcepart, out);
}

// Round 6
// 103.180 us; speedup vs baseline: 1.5111x; 1.0530x over previous
//
#include <hip/hip_runtime.h>
#include <hip/hip_bf16.h>
#include <math.h>

// Problem constants (B=512, D=768, H=256)
#define B 512
#define D 768
#define H 256
#define NN 128          // n = B/4
#define MM 256          // m = B/2
#define P_PAIRS 57280   // sum_{i=0}^{127} (511 - i) = 895 * 64 exactly
#define NPBLK 895       // pair-tiles of 64

typedef __attribute__((ext_vector_type(8))) __bf16 bf16x8;
typedef __attribute__((ext_vector_type(4))) __bf16 bf16x4;
typedef __attribute__((ext_vector_type(4))) float f32x4;

// MFMA 16x16x32 bf16 fragment layout (verified):
//   A[m = lane&15][k = (lane>>4)*8 + e]  /  B[k][n = lane&15] from row-major [n][k]
//   C/D: col = lane&15, row = (lane>>4)*4 + reg
//
// Restacked operand layout ("frag-tiles"): for a 16-row x 32-k tile (row-group g,
// k-step s), flat element index = ((g*S + s)*64 + q*16 + r)*8 + e  where the
// source element is M[16g + r][32s + 8q + e]. A wave-fragment load is then
// base + lane*16B: one dense, fully-coalesced 1 KB read (no gather).

// ---------------- K1: normalize z -> zA frag-tiles; W1,W2 -> frag-tiles ----------------
__global__ __launch_bounds__(256) void k_prep(const float* __restrict__ emb,
                                              const float* __restrict__ W1,
                                              const float* __restrict__ W2,
                                              __bf16* __restrict__ zA,    // 32 groups x 24 steps
                                              __bf16* __restrict__ W1A,   // 32 groups x 24 steps
                                              __bf16* __restrict__ W2s) { // 16 groups x 8 steps
    int bx = blockIdx.x;
    int t = threadIdx.x;
    if (bx < B) {
        // normalize row bx, write frag-tiled bf16
        int i = bx;
        float4 v4 = make_float4(0.f, 0.f, 0.f, 0.f);
        float ss = 0.f;
        if (t < D / 4) {
            v4 = *(const float4*)(emb + i * D + 4 * t);
            ss = v4.x * v4.x + v4.y * v4.y + v4.z * v4.z + v4.w * v4.w;
        }
        __shared__ float red[256];
        red[t] = ss;
        __syncthreads();
        for (int s = 128; s > 0; s >>= 1) {
            if (t < s) red[t] += red[t + s];
            __syncthreads();
        }
        float inv = 1.0f / fmaxf(sqrtf(red[0]), 1e-12f);
        if (t < D / 4) {
            bf16x4 o;
            o[0] = (__bf16)(v4.x * inv); o[1] = (__bf16)(v4.y * inv);
            o[2] = (__bf16)(v4.z * inv); o[3] = (__bf16)(v4.w * inv);
            int g = i >> 4, r = i & 15;
            int s24 = t >> 3, q = (t >> 1) & 3, e = (t & 1) * 4;
            *(bf16x4*)(zA + (((g * 24 + s24) * 64 + q * 16 + r) * 8 + e)) = o;
        }
    } else if (bx < B + 64) {
        // W2 frag-tiles: 64 blocks x 4 rows
        int n = (bx - B) * 4 + (t >> 6);
        int c = t & 63;                  // 4-col group: k = 4c
        float4 w = *(const float4*)(W2 + n * H + 4 * c);
        bf16x4 o;
        o[0] = (__bf16)w.x; o[1] = (__bf16)w.y; o[2] = (__bf16)w.z; o[3] = (__bf16)w.w;
        int g = n >> 4, r = n & 15;
        int s8 = c >> 3, q = (c >> 1) & 3, e = (c & 1) * 4;
        *(bf16x4*)(W2s + (((g * 8 + s8) * 64 + q * 16 + r) * 8 + e)) = o;
    } else {
        // W1 frag-tiles (stacked U|V rows): row n reads W1[n&255][(n>>8)*768 + k]
        int n = bx - B - 64;
        if (t < D / 4) {
            float4 w = *(const float4*)(W1 + (n & 255) * (2 * D) + (n >> 8) * D + 4 * t);
            bf16x4 o;
            o[0] = (__bf16)w.x; o[1] = (__bf16)w.y; o[2] = (__bf16)w.z; o[3] = (__bf16)w.w;
            int g = n >> 4, r = n & 15;
            int s24 = t >> 3, q = (t >> 1) & 3, e = (t & 1) * 4;
            *(bf16x4*)(W1A + (((g * 24 + s24) * 64 + q * 16 + r) * 8 + e)) = o;
        }
    }
}

// ---------------- K2: fused similarity stats + U'/V GEMMs (frag-tile loads) ----------------
__global__ __launch_bounds__(128) void k_sim_uv(const __bf16* __restrict__ zA,
                                                const __bf16* __restrict__ W1A,
                                                const float* __restrict__ b1,
                                                __bf16* __restrict__ Up,
                                                __bf16* __restrict__ Vv,
                                                float* __restrict__ esp,   // [8][128]
                                                float* __restrict__ slp) { // [8][128]
    int bx = blockIdx.x;
    int w = threadIdx.x >> 6;
    int lane = threadIdx.x & 63;
    int r = lane & 15, q = lane >> 4;

    if (bx < 32) {
        // ---- similarity stats: m-tile 16 (rows<128), wave n-tile 64 ----
        int gm = bx >> 2;                // m0 = gm*16
        int gn0 = (bx & 3) * 8 + w * 4;  // n0 = gn0*16
        int slot = (bx & 3) * 2 + w;
        f32x4 acc[4] = {};
        #pragma unroll 4
        for (int s = 0; s < D / 32; s++) {
            bf16x8 a = *(const bf16x8*)(zA + ((gm * 24 + s) * 64 + lane) * 8);
            #pragma unroll
            for (int nt = 0; nt < 4; nt++) {
                bf16x8 b = *(const bf16x8*)(zA + (((gn0 + nt) * 24 + s) * 64 + lane) * 8);
                acc[nt] = __builtin_amdgcn_mfma_f32_16x16x32_bf16(a, b, acc[nt], 0, 0, 0);
            }
        }
        #pragma unroll
        for (int rr = 0; rr < 4; rr++) {
            int irow = gm * 16 + q * 4 + rr;
            float es = 0.f, sl = 0.f;
            #pragma unroll
            for (int nt = 0; nt < 4; nt++) {
                int kcol = (gn0 + nt) * 16 + r;
                float C = acc[nt][rr];
                if (kcol != irow) es += expf(2.f * C);
                if (kcol > irow && kcol < NN) sl += 2.f * C;
            }
            #pragma unroll
            for (int m = 1; m <= 8; m <<= 1) {
                es += __shfl_xor(es, m);
                sl += __shfl_xor(sl, m);
            }
            if (r == 0) {
                esp[slot * NN + irow] = es;
                slp[slot * NN + irow] = sl;
            }
        }
    } else {
        // ---- U' = z@W1a^T + b1 ; V = z@W1b^T  (bf16 out, row-major) ----
        int bxu = bx - 32;
        int gm = (bxu >> 3) * 2 + w;     // m0 = gm*16
        int gn0 = (bxu & 7) * 4;         // n0 = gn0*16
        f32x4 acc[4] = {};
        #pragma unroll 4
        for (int s = 0; s < D / 32; s++) {
            bf16x8 a = *(const bf16x8*)(zA + ((gm * 24 + s) * 64 + lane) * 8);
            #pragma unroll
            for (int nt = 0; nt < 4; nt++) {
                bf16x8 b = *(const bf16x8*)(W1A + (((gn0 + nt) * 24 + s) * 64 + lane) * 8);
                acc[nt] = __builtin_amdgcn_mfma_f32_16x16x32_bf16(a, b, acc[nt], 0, 0, 0);
            }
        }
        #pragma unroll
        for (int nt = 0; nt < 4; nt++) {
            int n = (gn0 + nt) * 16 + r;
            float bias = (n < H) ? b1[n] : 0.f;
            #pragma unroll
            for (int rr = 0; rr < 4; rr++) {
                int m = gm * 16 + 4 * q + rr;
                float C = acc[nt][rr] + bias;
                if (n < H) Up[m * H + n] = (__bf16)C;
                else       Vv[m * H + (n - H)] = (__bf16)C;
            }
        }
    }
}

// ---------------- K3: pair MLP, frag-tiled W2, coalesced staging ----------------
// 895 blocks x 256 thr (4 waves; wave w -> output cols 64w..64w+63)
__global__ __launch_bounds__(256, 4) void k_pairs(const __bf16* __restrict__ Up,
                                                  const __bf16* __restrict__ Vv,
                                                  const __bf16* __restrict__ W2s,
                                                  const float* __restrict__ b2,
                                                  const float* __restrict__ W3,
                                                  const float* __restrict__ b3,
                                                  float* __restrict__ bcepart) {
    __shared__ __bf16 h1[64][264];       // 33.8 KB; row stride 528 B
    __shared__ int jj_s[64];
    __shared__ float redbuf[4][64];

    int tid = threadIdx.x;
    int w = tid >> 6, lane = tid & 63;
    int r = lane & 15, q = lane >> 4;
    int p0 = blockIdx.x * 64;

    // ---- (i,j) for row tid: i*(1023-i)/2 pairs precede row-block i ----
    if (tid < 64) {
        int p = p0 + tid;
        float disc = 1046529.f - 8.f * (float)p;   // 1023^2 - 8p, exact in fp32
        int i = (int)((1023.f - sqrtf(disc)) * 0.5f);
        if (i < 0) i = 0;
        if (i > NN - 1) i = NN - 1;
        while (i > 0 && i * (1023 - i) / 2 > p) i--;
        while ((i + 1) * (1022 - i) / 2 <= p) i++;
        int j = i + 1 + (p - i * (1023 - i) / 2);
        jj_s[tid] = (i << 16) | j;
    }
    __syncthreads();

    // ---- stage h1[row][:] = relu(U'[i] + V[j]) bf16; 4 lanes per row ----
    {
        int row = tid >> 2;              // 0..63
        int cq = tid & 3;                // col quarter: cols cq*64..cq*64+63
        int ij = jj_s[row];
        int i = ij >> 16, j = ij & 0xffff;
        const __bf16* up = Up + i * H + 64 * cq;
        const __bf16* vp = Vv + j * H + 64 * cq;
        #pragma unroll
        for (int c8 = 0; c8 < 8; c8++) {
            bf16x8 u8 = *(const bf16x8*)(up + 8 * c8);
            bf16x8 v8 = *(const bf16x8*)(vp + 8 * c8);
            bf16x8 hv;
            #pragma unroll
            for (int e = 0; e < 8; e++)
                hv[e] = (__bf16)fmaxf((float)u8[e] + (float)v8[e], 0.f);
            *(bf16x8*)&h1[row][64 * cq + 8 * c8] = hv;
        }
    }
    __syncthreads();

    // ---- MFMA: C[64 pairs][64 cols per wave] = h1 @ W2^T ----
    f32x4 acc[4][4] = {};                // [mt][nt]
    #pragma unroll
    for (int s = 0; s < 8; s++) {
        bf16x8 a[4], b[4];
        #pragma unroll
        for (int mt = 0; mt < 4; mt++)
            a[mt] = *(const bf16x8*)&h1[16 * mt + r][32 * s + 8 * q];
        #pragma unroll
        for (int nt = 0; nt < 4; nt++)
            b[nt] = *(const bf16x8*)(W2s + (((4 * w + nt) * 8 + s) * 64 + lane) * 8);
        #pragma unroll
        for (int mt = 0; mt < 4; mt++)
            #pragma unroll
            for (int nt = 0; nt < 4; nt++)
                acc[mt][nt] = __builtin_amdgcn_mfma_f32_16x16x32_bf16(a[mt], b[nt], acc[mt][nt], 0, 0, 0);
    }

    // ---- epilogue: h2 = relu(C + b2), partial logit = sum_n h2*W3 ----
    float part[4][4] = {};               // [mt][rr]
    #pragma unroll
    for (int nt = 0; nt < 4; nt++) {
        int n = 64 * w + 16 * nt + r;
        float b2v = b2[n], w3v = W3[n];
        #pragma unroll
        for (int mt = 0; mt < 4; mt++)
            #pragma unroll
            for (int rr = 0; rr < 4; rr++) {
                float h2 = fmaxf(acc[mt][nt][rr] + b2v, 0.f);
                part[mt][rr] += h2 * w3v;
            }
    }
    #pragma unroll
    for (int mt = 0; mt < 4; mt++)
        #pragma unroll
        for (int rr = 0; rr < 4; rr++) {
            float v = part[mt][rr];
            #pragma unroll
            for (int m = 1; m <= 8; m <<= 1) v += __shfl_xor(v, m);
            if (r == 0) redbuf[w][16 * mt + 4 * q + rr] = v;
        }
    __syncthreads();

    if (tid < 64) {
        int j = jj_s[tid] & 0xffff;
        float logit = redbuf[0][tid] + redbuf[1][tid] +
                      redbuf[2][tid] + redbuf[3][tid] + b3[0];
        float label = (j < MM) ? 1.f : 0.f;
        float lsum = fmaxf(logit, 0.f) - logit * label +
                     log1pf(expf(-fabsf(logit)));
        #pragma unroll
        for (int off = 32; off > 0; off >>= 1) lsum += __shfl_down(lsum, off);
        if (tid == 0) bcepart[blockIdx.x] = lsum;   // plain store, no atomic
    }
}

// ---------------- K4: final combine ----------------
__global__ __launch_bounds__(256) void k_final(const float* __restrict__ esp,
                                               const float* __restrict__ slp,
                                               const float* __restrict__ bcepart,
                                               float* __restrict__ out) {
    __shared__ float red[256];
    int t = threadIdx.x;

    float s = 0.f;
    for (int p = t; p < NPBLK; p += 256) s += bcepart[p];
    red[t] = s;
    __syncthreads();
    for (int st = 128; st > 0; st >>= 1) {
        if (t < st) red[t] += red[t + st];
        __syncthreads();
    }
    float bce_total = red[0];
    __syncthreads();

    float v = 0.f;
    if (t < NN) {
        float es = 0.f, sl = 0.f;
        #pragma unroll
        for (int s8 = 0; s8 < 8; s8++) {
            es += esp[s8 * NN + t];
            sl += slp[s8 * NN + t];
        }
        v = (float)(NN - 1 - t) * logf(es) - sl;
    }
    red[t] = v;
    __syncthreads();
    for (int st = 128; st > 0; st >>= 1) {
        if (t < st) red[t] += red[t + st];
        __syncthreads();
    }
    if (t == 0) {
        float closs = (-2.0f * (float)(NN - 1) / (float)NN) * red[0];
        out[0] = closs + bce_total / (float)P_PAIRS;
    }
}

extern "C" void kernel_launch(void* const* d_in, const int* in_sizes, int n_in,
                              void* d_out, int out_size, void* d_ws, size_t ws_size,
                              hipStream_t stream) {
    const float* emb = (const float*)d_in[0];
    const float* W1  = (const float*)d_in[1];
    const float* b1  = (const float*)d_in[2];
    const float* W2  = (const float*)d_in[3];
    const float* b2  = (const float*)d_in[4];
    const float* W3  = (const float*)d_in[5];
    const float* b3  = (const float*)d_in[6];
    float* out = (float*)d_out;

    float* ws = (float*)d_ws;
    float* esp     = ws;                         // 8*128
    float* slp     = ws + 1024;                  // 8*128
    float* bcepart = ws + 2048;                  // 895
    __bf16* zA  = (__bf16*)(ws + 3072);          // 512*768 frag-tiled
    __bf16* W1A = zA + B * D;                    // 512*768 frag-tiled
    __bf16* W2s = W1A + 2 * H * D;               // 256*256 frag-tiled
    __bf16* Up  = W2s + H * H;                   // 512*256 row-major
    __bf16* Vv  = Up + B * H;                    // 512*256 row-major

    k_prep<<<B + 64 + 2 * H, 256, 0, stream>>>(emb, W1, W2, zA, W1A, W2s);
    k_sim_uv<<<160, 128, 0, stream>>>(zA, W1A, b1, Up, Vv, esp, slp);
    k_pairs<<<NPBLK, 256, 0, stream>>>(Up, Vv, W2s, b2, W3, b3, bcepart);
    k_final<<<1, 256, 0, stream>>>(esp, slp, bcepart, out);
}

// Round 7
// 101.267 us; speedup vs baseline: 1.5396x; 1.0189x over previous
//
#include <hip/hip_runtime.h>
#include <hip/hip_bf16.h>
#include <math.h>

// Problem constants (B=512, D=768, H=256)
#define B 512
#define D 768
#define H 256
#define NN 128          // n = B/4
#define MM 256          // m = B/2
#define P_PAIRS 57280   // sum_{i=0}^{127} (511 - i)
#define NPBLK_P 448     // pair-tiles of 128 (last one half-padded)

typedef _Float16 f16x8 __attribute__((ext_vector_type(8)));
typedef _Float16 f16x4 __attribute__((ext_vector_type(4)));
typedef float f32x4 __attribute__((ext_vector_type(4)));

// MFMA 16x16x32 (f16/bf16 same layout):
//   A[m = lane&15][k = (lane>>4)*8 + e]; B from row-major [n][k] same pattern
//   C/D: col = lane&15, row = (lane>>4)*4 + reg
// Frag-tile layout: flat = ((g*S + s)*64 + lane)*8 + e  <=>  M[16g + (lane&15)][32s + (lane>>4)*8 + e]

// ---------------- K1: prep -> zH, W1H frag-tiles (S=24); W2H frag-tiles (S=8); all f16 ----------------
__global__ __launch_bounds__(256) void k_prep(const float* __restrict__ emb,
                                              const float* __restrict__ W1,
                                              const float* __restrict__ W2,
                                              _Float16* __restrict__ zH,
                                              _Float16* __restrict__ W1H,
                                              _Float16* __restrict__ W2H) {
    int bx = blockIdx.x;
    int tid = threadIdx.x;
    int w = tid >> 6, lane = tid & 63;

    if (bx < 32) {
        // ---- z group g: rows 16g..16g+15, normalize + frag-tile ----
        int g = bx;
        __shared__ float invs[16];
        // phase 1: norms (wave w -> rows 4w..4w+3)
        for (int rr = 0; rr < 4; rr++) {
            int row = 16 * g + 4 * w + rr;
            const float* rp = emb + row * D;
            float ss = 0.f;
            #pragma unroll
            for (int it = 0; it < 12; it++) {
                float v = rp[lane + 64 * it];
                ss += v * v;
            }
            #pragma unroll
            for (int m = 1; m <= 32; m <<= 1) ss += __shfl_xor(ss, m);
            if (lane == 0) invs[4 * w + rr] = 1.0f / fmaxf(sqrtf(ss), 1e-12f);
        }
        __syncthreads();
        // phase 2: frag-tile write (coalesced 16B/lane)
        for (int it = 0; it < 6; it++) {
            int chunk = it * 256 + tid;          // 0..1535
            int s = chunk >> 6, lc = chunk & 63;
            int q = lc >> 4, r = lc & 15;
            const float* src = emb + (16 * g + r) * D + 32 * s + 8 * q;
            float inv = invs[r];
            float4 a = *(const float4*)src;
            float4 b = *(const float4*)(src + 4);
            f16x8 o;
            o[0] = (_Float16)(a.x * inv); o[1] = (_Float16)(a.y * inv);
            o[2] = (_Float16)(a.z * inv); o[3] = (_Float16)(a.w * inv);
            o[4] = (_Float16)(b.x * inv); o[5] = (_Float16)(b.y * inv);
            o[6] = (_Float16)(b.z * inv); o[7] = (_Float16)(b.w * inv);
            *(f16x8*)(zH + ((g * 24 + s) * 64 + lc) * 8) = o;
        }
    } else if (bx < 64) {
        // ---- W1H group g: row n = 16g+r reads W1[n&255][(n>>8)*768 + k] ----
        int g = bx - 32;
        for (int it = 0; it < 6; it++) {
            int chunk = it * 256 + tid;
            int s = chunk >> 6, lc = chunk & 63;
            int q = lc >> 4, r = lc & 15;
            int n = 16 * g + r;
            const float* src = W1 + (n & 255) * (2 * D) + (n >> 8) * D + 32 * s + 8 * q;
            float4 a = *(const float4*)src;
            float4 b = *(const float4*)(src + 4);
            f16x8 o;
            o[0] = (_Float16)a.x; o[1] = (_Float16)a.y; o[2] = (_Float16)a.z; o[3] = (_Float16)a.w;
            o[4] = (_Float16)b.x; o[5] = (_Float16)b.y; o[6] = (_Float16)b.z; o[7] = (_Float16)b.w;
            *(f16x8*)(W1H + ((g * 24 + s) * 64 + lc) * 8) = o;
        }
    } else {
        // ---- W2H group g (16 groups, S=8) ----
        int g = bx - 64;
        for (int it = 0; it < 2; it++) {
            int chunk = it * 256 + tid;          // 0..511
            int s = chunk >> 6, lc = chunk & 63;
            int q = lc >> 4, r = lc & 15;
            const float* src = W2 + (16 * g + r) * H + 32 * s + 8 * q;
            float4 a = *(const float4*)src;
            float4 b = *(const float4*)(src + 4);
            f16x8 o;
            o[0] = (_Float16)a.x; o[1] = (_Float16)a.y; o[2] = (_Float16)a.z; o[3] = (_Float16)a.w;
            o[4] = (_Float16)b.x; o[5] = (_Float16)b.y; o[6] = (_Float16)b.z; o[7] = (_Float16)b.w;
            *(f16x8*)(W2H + ((g * 8 + s) * 64 + lc) * 8) = o;
        }
    }
}

// ---------------- K2: U' = z@W1a^T + b1 ; V = z@W1b^T (f16 out); 512 single-wave tiles ----------------
__global__ __launch_bounds__(256) void k_uv(const _Float16* __restrict__ zH,
                                            const _Float16* __restrict__ W1H,
                                            const float* __restrict__ b1,
                                            _Float16* __restrict__ Up,
                                            _Float16* __restrict__ Vv) {
    int w = threadIdx.x >> 6;
    int lane = threadIdx.x & 63;
    int r = lane & 15, q = lane >> 4;
    int tile = blockIdx.x * 4 + w;       // 0..511
    int gm = tile >> 4;                  // 0..31
    int gnp = tile & 15;                 // n-tile pair: n-tiles gnp*2, gnp*2+1

    f32x4 acc[2] = {};
    #pragma unroll 4
    for (int s = 0; s < 24; s++) {
        f16x8 a = *(const f16x8*)(zH + ((gm * 24 + s) * 64 + lane) * 8);
        #pragma unroll
        for (int nt = 0; nt < 2; nt++) {
            f16x8 b = *(const f16x8*)(W1H + (((gnp * 2 + nt) * 24 + s) * 64 + lane) * 8);
            acc[nt] = __builtin_amdgcn_mfma_f32_16x16x32_f16(a, b, acc[nt], 0, 0, 0);
        }
    }
    #pragma unroll
    for (int nt = 0; nt < 2; nt++) {
        int n = (gnp * 2 + nt) * 16 + r;
        float bias = (n < H) ? b1[n] : 0.f;
        #pragma unroll
        for (int rr = 0; rr < 4; rr++) {
            int m = gm * 16 + 4 * q + rr;
            float C = acc[nt][rr] + bias;
            if (n < H) Up[m * H + n] = (_Float16)C;
            else       Vv[m * H + (n - H)] = (_Float16)C;
        }
    }
}

// ---------------- K3: pair MLP (128-pair tiles) + similarity stats blocks ----------------
// blocks [0,448): pairs; blocks [448,464): sim stats
__global__ __launch_bounds__(256, 2) void k_pairs(const _Float16* __restrict__ Up,
                                                  const _Float16* __restrict__ Vv,
                                                  const _Float16* __restrict__ W2H,
                                                  const _Float16* __restrict__ zH,
                                                  const float* __restrict__ b2,
                                                  const float* __restrict__ W3,
                                                  const float* __restrict__ b3,
                                                  float* __restrict__ bcepart,
                                                  float* __restrict__ esp,   // [8][128]
                                                  float* __restrict__ slp) { // [8][128]
    int tid = threadIdx.x;
    int w = tid >> 6, lane = tid & 63;
    int r = lane & 15, q = lane >> 4;
    int bx = blockIdx.x;

    if (bx >= NPBLK_P) {
        // ---- similarity stats: wave tile t = (bx-448)*4+w: gm = t>>3, cols 64*(t&7) ----
        int t = (bx - NPBLK_P) * 4 + w;  // 0..63
        int gm = t >> 3;                 // 0..7 (rows < 128)
        int slot = t & 7;
        int gn0 = slot * 4;
        f32x4 acc[4] = {};
        #pragma unroll 4
        for (int s = 0; s < 24; s++) {
            f16x8 a = *(const f16x8*)(zH + ((gm * 24 + s) * 64 + lane) * 8);
            #pragma unroll
            for (int nt = 0; nt < 4; nt++) {
                f16x8 b = *(const f16x8*)(zH + (((gn0 + nt) * 24 + s) * 64 + lane) * 8);
                acc[nt] = __builtin_amdgcn_mfma_f32_16x16x32_f16(a, b, acc[nt], 0, 0, 0);
            }
        }
        #pragma unroll
        for (int rr = 0; rr < 4; rr++) {
            int irow = gm * 16 + q * 4 + rr;
            float es = 0.f, sl = 0.f;
            #pragma unroll
            for (int nt = 0; nt < 4; nt++) {
                int kcol = (gn0 + nt) * 16 + r;
                float C = acc[nt][rr];
                if (kcol != irow) es += expf(2.f * C);
                if (kcol > irow && kcol < NN) sl += 2.f * C;
            }
            #pragma unroll
            for (int m = 1; m <= 8; m <<= 1) {
                es += __shfl_xor(es, m);
                sl += __shfl_xor(sl, m);
            }
            if (r == 0) {
                esp[slot * NN + irow] = es;
                slp[slot * NN + irow] = sl;
            }
        }
        return;
    }

    // ---- pair blocks ----
    __shared__ _Float16 h1[128][264];    // 66 KB
    __shared__ int jj_s[128];
    __shared__ float redbuf[4][128];
    __shared__ float red2[2];

    int p0 = bx * 128;
    if (tid < 128) {
        int p = p0 + tid;
        if (p >= P_PAIRS) p = P_PAIRS - 1;     // pad rows duplicate last pair (masked later)
        float disc = 1046529.f - 8.f * (float)p;
        int i = (int)((1023.f - sqrtf(disc)) * 0.5f);
        if (i < 0) i = 0;
        if (i > NN - 1) i = NN - 1;
        while (i > 0 && i * (1023 - i) / 2 > p) i--;
        while ((i + 1) * (1022 - i) / 2 <= p) i++;
        int j = i + 1 + (p - i * (1023 - i) / 2);
        jj_s[tid] = (i << 16) | j;
    }
    __syncthreads();

    // ---- stage h1 = relu(U'[i] + V[j]) f16; units: (row, col-quarter) ----
    {
        #pragma unroll
        for (int uu = 0; uu < 2; uu++) {
            int u = uu * 256 + tid;      // 0..511
            int row = u >> 2, cq = u & 3;
            int ij = jj_s[row];
            int i = ij >> 16, j = ij & 0xffff;
            const _Float16* up = Up + i * H + 64 * cq;
            const _Float16* vp = Vv + j * H + 64 * cq;
            #pragma unroll
            for (int c8 = 0; c8 < 8; c8++) {
                f16x8 u8 = *(const f16x8*)(up + 8 * c8);
                f16x8 v8 = *(const f16x8*)(vp + 8 * c8);
                f16x8 zero = {};
                f16x8 hv = __builtin_elementwise_max(u8 + v8, zero);
                *(f16x8*)&h1[row][64 * cq + 8 * c8] = hv;
            }
        }
    }
    __syncthreads();

    // ---- MFMA: C[128 pairs][64 cols per wave] = h1 @ W2^T ----
    f32x4 acc[8][4] = {};                // [mt][nt]
    #pragma unroll
    for (int s = 0; s < 8; s++) {
        f16x8 b[4];
        #pragma unroll
        for (int nt = 0; nt < 4; nt++)
            b[nt] = *(const f16x8*)(W2H + (((4 * w + nt) * 8 + s) * 64 + lane) * 8);
        #pragma unroll
        for (int mt = 0; mt < 8; mt++) {
            f16x8 a = *(const f16x8*)&h1[16 * mt + r][32 * s + 8 * q];
            #pragma unroll
            for (int nt = 0; nt < 4; nt++)
                acc[mt][nt] = __builtin_amdgcn_mfma_f32_16x16x32_f16(a, b[nt], acc[mt][nt], 0, 0, 0);
        }
    }

    // ---- epilogue: h2 = relu(C + b2), partial logit = sum_n h2*W3 ----
    float b2v[4], w3v[4];
    #pragma unroll
    for (int nt = 0; nt < 4; nt++) {
        int n = 64 * w + 16 * nt + r;
        b2v[nt] = b2[n];
        w3v[nt] = W3[n];
    }
    #pragma unroll
    for (int mt = 0; mt < 8; mt++) {
        float part[4] = {0.f, 0.f, 0.f, 0.f};
        #pragma unroll
        for (int nt = 0; nt < 4; nt++)
            #pragma unroll
            for (int rr = 0; rr < 4; rr++) {
                float h2 = fmaxf(acc[mt][nt][rr] + b2v[nt], 0.f);
                part[rr] += h2 * w3v[nt];
            }
        #pragma unroll
        for (int rr = 0; rr < 4; rr++) {
            float v = part[rr];
            #pragma unroll
            for (int m = 1; m <= 8; m <<= 1) v += __shfl_xor(v, m);
            if (r == 0) redbuf[w][16 * mt + 4 * q + rr] = v;
        }
    }
    __syncthreads();

    if (tid < 128) {
        int p = p0 + tid;
        int j = jj_s[tid] & 0xffff;
        float lsum = 0.f;
        if (p < P_PAIRS) {
            float logit = redbuf[0][tid] + redbuf[1][tid] +
                          redbuf[2][tid] + redbuf[3][tid] + b3[0];
            float label = (j < MM) ? 1.f : 0.f;
            lsum = fmaxf(logit, 0.f) - logit * label + log1pf(expf(-fabsf(logit)));
        }
        #pragma unroll
        for (int off = 32; off > 0; off >>= 1) lsum += __shfl_down(lsum, off);
        if ((tid & 63) == 0) red2[tid >> 6] = lsum;
    }
    __syncthreads();
    if (tid == 0) bcepart[bx] = red2[0] + red2[1];
}

// ---------------- K4: final combine ----------------
__global__ __launch_bounds__(256) void k_final(const float* __restrict__ esp,
                                               const float* __restrict__ slp,
                                               const float* __restrict__ bcepart,
                                               float* __restrict__ out) {
    __shared__ float red[256];
    int t = threadIdx.x;

    float s = 0.f;
    for (int p = t; p < NPBLK_P; p += 256) s += bcepart[p];
    red[t] = s;
    __syncthreads();
    for (int st = 128; st > 0; st >>= 1) {
        if (t < st) red[t] += red[t + st];
        __syncthreads();
    }
    float bce_total = red[0];
    __syncthreads();

    float v = 0.f;
    if (t < NN) {
        float es = 0.f, sl = 0.f;
        #pragma unroll
        for (int s8 = 0; s8 < 8; s8++) {
            es += esp[s8 * NN + t];
            sl += slp[s8 * NN + t];
        }
        v = (float)(NN - 1 - t) * logf(es) - sl;
    }
    red[t] = v;
    __syncthreads();
    for (int st = 128; st > 0; st >>= 1) {
        if (t < st) red[t] += red[t + st];
        __syncthreads();
    }
    if (t == 0) {
        float closs = (-2.0f * (float)(NN - 1) / (float)NN) * red[0];
        out[0] = closs + bce_total / (float)P_PAIRS;
    }
}

extern "C" void kernel_launch(void* const* d_in, const int* in_sizes, int n_in,
                              void* d_out, int out_size, void* d_ws, size_t ws_size,
                              hipStream_t stream) {
    const float* emb = (const float*)d_in[0];
    const float* W1  = (const float*)d_in[1];
    const float* b1  = (const float*)d_in[2];
    const float* W2  = (const float*)d_in[3];
    const float* b2  = (const float*)d_in[4];
    const float* W3  = (const float*)d_in[5];
    const float* b3  = (const float*)d_in[6];
    float* out = (float*)d_out;

    float* ws = (float*)d_ws;
    float* esp     = ws;                         // 8*128
    float* slp     = ws + 1024;                  // 8*128
    float* bcepart = ws + 2048;                  // 448
    _Float16* zH  = (_Float16*)(ws + 2560);      // 512*768
    _Float16* W1H = zH + B * D;                  // 512*768
    _Float16* W2H = W1H + 2 * H * D;             // 256*256
    _Float16* Up  = W2H + H * H;                 // 512*256
    _Float16* Vv  = Up + B * H;                  // 512*256

    k_prep<<<80, 256, 0, stream>>>(emb, W1, W2, zH, W1H, W2H);
    k_uv<<<128, 256, 0, stream>>>(zH, W1H, b1, Up, Vv);
    k_pairs<<<NPBLK_P + 16, 256, 0, stream>>>(Up, Vv, W2H, zH, b2, W3, b3,
                                              bcepart, esp, slp);
    k_final<<<1, 256, 0, stream>>>(esp, slp, bcepart, out);
}